// Round 3
// baseline (322.554 us; speedup 1.0000x reference)
//
#include <hip/hip_runtime.h>
#include <hip/hip_bf16.h>

#define B_    32
#define L_    4096
#define H_    32
#define HKV_  2
#define GQ_   16
#define D_    128
#define HID_  4096
#define FFN_  13696
#define NQKV_ 4608
#define ROT_  64
#define EPS_  1e-5f

#define WAVE_POS_ 64
#define NSPLIT_   64   // L_ / WAVE_POS_

typedef __attribute__((ext_vector_type(8))) __bf16 bf16x8;
typedef __attribute__((ext_vector_type(4))) float  f32x4;

// ---------------------------------------------------------------- rmsnorm1
__global__ __launch_bounds__(256) void rmsnorm1_k(const float* __restrict__ x,
                                                  const float* __restrict__ w,
                                                  __bf16* __restrict__ out)
{
    int b = blockIdx.x;
    const float* row = x + (size_t)b * HID_;
    float vals[16];
    float ss = 0.f;
#pragma unroll
    for (int i = 0; i < 16; ++i) {
        vals[i] = row[threadIdx.x + i * 256];
        ss += vals[i] * vals[i];
    }
#pragma unroll
    for (int m = 1; m < 64; m <<= 1) ss += __shfl_xor(ss, m);
    __shared__ float wred[4];
    if ((threadIdx.x & 63) == 0) wred[threadIdx.x >> 6] = ss;
    __syncthreads();
    ss = wred[0] + wred[1] + wred[2] + wred[3];
    float rs = rsqrtf(ss / HID_ + EPS_);
#pragma unroll
    for (int i = 0; i < 16; ++i) {
        int idx = threadIdx.x + i * 256;
        out[(size_t)b * HID_ + idx] = (__bf16)(w[idx] * vals[i] * rs);
    }
}

// ---------------------------------------------------------------- skinny GEMM
// A: [32][K] bf16 row-major.  W: [K][N] f32.  Cp: [KSPLIT][32][N] f32 partials.
// 2-deep ping-pong prefetch (pf0/tileA, pf1/tileB); stride-34 LDS (2-way free).
template<int K, int N, int KSPLIT>
__global__ __launch_bounds__(256) void gemm16(const __bf16* __restrict__ A,
                                              const float* __restrict__ W,
                                              float* __restrict__ Cp)
{
    static_assert(K % 32 == 0, "K");
    constexpr int ksteps = K / 32;
    constexpr int nch    = KSPLIT * 4;
    const int lane = threadIdx.x & 63;
    const int wid  = threadIdx.x >> 6;
    const int n0   = blockIdx.x * 32;
    const int r    = lane & 15;
    const int g4   = lane >> 4;
    const int cid  = blockIdx.y * 4 + wid;
    const int s0   = (ksteps * cid) / nch;
    const int s1   = (ksteps * (cid + 1)) / nch;
    const int kk_b = lane >> 3;        // 0..7
    const int c4   = (lane & 7) * 4;   // 0,4,..,28

    __shared__ __bf16 tA[4][32][34];
    __shared__ __bf16 tB[4][32][34];
    __bf16 (*ta)[34] = tA[wid];
    __bf16 (*tb)[34] = tB[wid];

    f32x4 acc00 = {0.f,0.f,0.f,0.f}, acc01 = acc00, acc10 = acc00, acc11 = acc00;
    const __bf16* a0p = A + (size_t)r * K;
    const __bf16* a1p = A + (size_t)(r + 16) * K;
    const float*  wbase = W + n0 + c4;

    float4 pf0[4], pf1[4];
    auto issue0 = [&](int s) {
        const float* p = wbase + (size_t)(s * 32 + kk_b) * N;
#pragma unroll
        for (int it = 0; it < 4; ++it) pf0[it] = *(const float4*)(p + (size_t)(it * 8) * N);
    };
    auto issue1 = [&](int s) {
        const float* p = wbase + (size_t)(s * 32 + kk_b) * N;
#pragma unroll
        for (int it = 0; it < 4; ++it) pf1[it] = *(const float4*)(p + (size_t)(it * 8) * N);
    };
    auto clampi = [&](int s) { return s < s1 ? s : s1 - 1; };

    if (s0 < s1) {
        issue0(s0);
        issue1(clampi(s0 + 1));
    }
    for (int s = s0; s < s1; s += 2) {
        // ---------- phase A : k-step s from pf0/tileA ----------
        bf16x8 av0 = *(const bf16x8*)(a0p + s * 32 + g4 * 8);
        bf16x8 av1 = *(const bf16x8*)(a1p + s * 32 + g4 * 8);
#pragma unroll
        for (int it = 0; it < 4; ++it) {
            int kk = it * 8 + kk_b;
            ta[c4 + 0][kk] = (__bf16)pf0[it].x;
            ta[c4 + 1][kk] = (__bf16)pf0[it].y;
            ta[c4 + 2][kk] = (__bf16)pf0[it].z;
            ta[c4 + 3][kk] = (__bf16)pf0[it].w;
        }
        issue0(clampi(s + 2));
        asm volatile("s_waitcnt lgkmcnt(0)" ::: "memory");
        __builtin_amdgcn_sched_barrier(0);
        {
            bf16x8 b0 = *(const bf16x8*)&ta[r][g4 * 8];
            bf16x8 b1 = *(const bf16x8*)&ta[r + 16][g4 * 8];
            acc00 = __builtin_amdgcn_mfma_f32_16x16x32_bf16(av0, b0, acc00, 0, 0, 0);
            acc10 = __builtin_amdgcn_mfma_f32_16x16x32_bf16(av1, b0, acc10, 0, 0, 0);
            acc01 = __builtin_amdgcn_mfma_f32_16x16x32_bf16(av0, b1, acc01, 0, 0, 0);
            acc11 = __builtin_amdgcn_mfma_f32_16x16x32_bf16(av1, b1, acc11, 0, 0, 0);
        }
        // ---------- phase B : k-step s+1 from pf1/tileB ----------
        if (s + 1 < s1) {
            bf16x8 av2 = *(const bf16x8*)(a0p + (s + 1) * 32 + g4 * 8);
            bf16x8 av3 = *(const bf16x8*)(a1p + (s + 1) * 32 + g4 * 8);
#pragma unroll
            for (int it = 0; it < 4; ++it) {
                int kk = it * 8 + kk_b;
                tb[c4 + 0][kk] = (__bf16)pf1[it].x;
                tb[c4 + 1][kk] = (__bf16)pf1[it].y;
                tb[c4 + 2][kk] = (__bf16)pf1[it].z;
                tb[c4 + 3][kk] = (__bf16)pf1[it].w;
            }
            issue1(clampi(s + 3));
            asm volatile("s_waitcnt lgkmcnt(0)" ::: "memory");
            __builtin_amdgcn_sched_barrier(0);
            bf16x8 b0 = *(const bf16x8*)&tb[r][g4 * 8];
            bf16x8 b1 = *(const bf16x8*)&tb[r + 16][g4 * 8];
            acc00 = __builtin_amdgcn_mfma_f32_16x16x32_bf16(av2, b0, acc00, 0, 0, 0);
            acc10 = __builtin_amdgcn_mfma_f32_16x16x32_bf16(av3, b0, acc10, 0, 0, 0);
            acc01 = __builtin_amdgcn_mfma_f32_16x16x32_bf16(av2, b1, acc01, 0, 0, 0);
            acc11 = __builtin_amdgcn_mfma_f32_16x16x32_bf16(av3, b1, acc11, 0, 0, 0);
        }
    }

    __shared__ float red[4][32][32];
#pragma unroll
    for (int i = 0; i < 4; ++i) {
        red[wid][g4 * 4 + i][r]           = acc00[i];
        red[wid][g4 * 4 + i][16 + r]      = acc01[i];
        red[wid][16 + g4 * 4 + i][r]      = acc10[i];
        red[wid][16 + g4 * 4 + i][16 + r] = acc11[i];
    }
    __syncthreads();
    for (int idx = threadIdx.x; idx < 1024; idx += 256) {
        int row = idx >> 5, col = idx & 31;
        float v = red[0][row][col] + red[1][row][col] + red[2][row][col] + red[3][row][col];
        Cp[((size_t)blockIdx.y * 32 + row) * N + n0 + col] = v;
    }
}

// ---------------------------------------------------------------- qkv epilogue (+bias, rope, split)
__global__ __launch_bounds__(256) void qkv_epi_k(const float* __restrict__ part, // [8][32][NQKV_]
                                                 const float* __restrict__ bias,
                                                 const int* __restrict__ ctxl,
                                                 __bf16* __restrict__ qbf,    // [32][4096] roped, *D^-0.5
                                                 float* __restrict__ knew,    // [32][2][128] roped
                                                 float* __restrict__ vnew)    // [32][2][128]
{
    __shared__ float rowv[NQKV_];
    __shared__ float cs[32], sn[32];
    int b = blockIdx.x;
    int pos = ctxl[b];
    if (threadIdx.x < 32) {
        int t = threadIdx.x;
        float inv = powf(10000.f, -(float)t * (1.0f / 32.0f));
        float f = (float)pos * inv;
        float sv, cv; sincosf(f, &sv, &cv);
        cs[t] = cv; sn[t] = sv;
    }
    for (int i = threadIdx.x; i < NQKV_; i += 256) {
        float v = bias[i];
#pragma unroll
        for (int p = 0; p < 8; ++p) v += part[((size_t)p * B_ + b) * NQKV_ + i];
        rowv[i] = v;
    }
    __syncthreads();
    const float qscale = 0.08838834764831845f; // 1/sqrt(128)
    for (int i = threadIdx.x; i < HID_; i += 256) {
        int d = i & 127;
        float o;
        if (d < ROT_) {
            int t = d >> 1;
            float cv = cs[t], sv = sn[t];
            float x1 = rowv[i & ~1], x2 = rowv[i | 1];
            o = (d & 1) ? (x2 * cv + x1 * sv) : (x1 * cv - x2 * sv);
        } else o = rowv[i];
        qbf[(size_t)b * HID_ + i] = (__bf16)(o * qscale);
    }
    for (int i = threadIdx.x; i < HKV_ * D_; i += 256) {
        int d = i & 127;
        float o;
        if (d < ROT_) {
            int t = d >> 1;
            float cv = cs[t], sv = sn[t];
            float x1 = rowv[HID_ + (i & ~1)], x2 = rowv[HID_ + (i | 1)];
            o = (d & 1) ? (x2 * cv + x1 * sv) : (x1 * cv - x2 * sv);
        } else o = rowv[HID_ + i];
        knew[(size_t)b * HKV_ * D_ + i] = o;
        vnew[(size_t)b * HKV_ * D_ + i] = rowv[HID_ + HKV_ * D_ + i];
    }
}

// ---------------------------------------------------------------- flash-decode attention (partials)
// part: [B*HKV][NSPLIT_][16][130]  (128 acc, m, l) per head
__global__ __launch_bounds__(256) void attn_k(const float* __restrict__ kc,
                                              const float* __restrict__ vc,
                                              const float* __restrict__ knew,
                                              const float* __restrict__ vnew,
                                              const __bf16* __restrict__ qbf,
                                              const int* __restrict__ ctxl,
                                              float* __restrict__ part)
{
    const int bg  = blockIdx.x;            // 0..63
    const int b   = bg >> 1, g = bg & 1;
    const int wid = threadIdx.x >> 6;
    const int split = blockIdx.y * 4 + wid;  // 0..NSPLIT_-1
    const int ctx = ctxl[b];
    const int p0  = split * WAVE_POS_;
    __shared__ __bf16 plds_all[4][16][40];
    if (p0 > ctx) return;
    const int pend = min(p0 + WAVE_POS_ - 1, ctx);
    const int lane = threadIdx.x & 63;
    const int r = lane & 15, g4 = lane >> 4;

    bf16x8 qf[4];
    {
        const __bf16* qp = qbf + (size_t)b * HID_ + (g * GQ_ + r) * D_ + g4 * 8;
#pragma unroll
        for (int kk = 0; kk < 4; ++kk) qf[kk] = *(const bf16x8*)(qp + kk * 32);
    }
    f32x4 acc[8];
#pragma unroll
    for (int dt = 0; dt < 8; ++dt) acc[dt] = (f32x4){0.f,0.f,0.f,0.f};
    float m_run[4], l_run[4];
#pragma unroll
    for (int i = 0; i < 4; ++i) { m_run[i] = -1e30f; l_run[i] = 0.f; }

    auto plds = plds_all[wid];
    const float* kbase = kc + ((size_t)b * L_ * HKV_ + g) * D_;
    const float* vbase = vc + ((size_t)b * L_ * HKV_ + g) * D_;
    const float* knp = knew + (size_t)(b * HKV_ + g) * D_;
    const float* vnp = vnew + (size_t)(b * HKV_ + g) * D_;

    for (int pc = p0; pc <= pend; pc += 32) {
        // ---- QK^T : scores S[h][p], h=g4*4+i, p = pc + pt*16 + r
        f32x4 sf[2];
#pragma unroll
        for (int pt = 0; pt < 2; ++pt) {
            int pos = pc + pt * 16 + r;
            const float* krow = (pos == ctx) ? knp : kbase + (size_t)pos * (HKV_ * D_);
            f32x4 s = {0.f,0.f,0.f,0.f};
#pragma unroll
            for (int kk = 0; kk < 4; ++kk) {
                const float4* kp = (const float4*)(krow + kk * 32 + g4 * 8);
                float4 fa = kp[0], fb = kp[1];
                bf16x8 kf = { (__bf16)fa.x, (__bf16)fa.y, (__bf16)fa.z, (__bf16)fa.w,
                              (__bf16)fb.x, (__bf16)fb.y, (__bf16)fb.z, (__bf16)fb.w };
                s = __builtin_amdgcn_mfma_f32_16x16x32_bf16(qf[kk], kf, s, 0, 0, 0);
            }
            sf[pt] = s;
        }
        // ---- mask
#pragma unroll
        for (int pt = 0; pt < 2; ++pt) {
            int pos = pc + pt * 16 + r;
            if (pos > ctx) {
#pragma unroll
                for (int i = 0; i < 4; ++i) sf[pt][i] = -1e30f;
            }
        }
        // ---- online softmax (per-head chunk max via 16-lane butterfly)
#pragma unroll
        for (int i = 0; i < 4; ++i) {
            float mv = fmaxf(sf[0][i], sf[1][i]);
            mv = fmaxf(mv, __shfl_xor(mv, 1));
            mv = fmaxf(mv, __shfl_xor(mv, 2));
            mv = fmaxf(mv, __shfl_xor(mv, 4));
            mv = fmaxf(mv, __shfl_xor(mv, 8));
            float mnew = fmaxf(m_run[i], mv);
            float sc = __expf(m_run[i] - mnew);
            l_run[i] *= sc;
            m_run[i] = mnew;
#pragma unroll
            for (int dt = 0; dt < 8; ++dt) acc[dt][i] *= sc;
        }
        // ---- exp, stage P into LDS in PV-A-fragment layout
#pragma unroll
        for (int pt = 0; pt < 2; ++pt) {
#pragma unroll
            for (int i = 0; i < 4; ++i) {
                float e = __expf(sf[pt][i] - m_run[i]);
                l_run[i] += e;
                plds[g4 * 4 + i][pt * 16 + r] = (__bf16)e;
            }
        }
        asm volatile("s_waitcnt lgkmcnt(0)" ::: "memory");
        __builtin_amdgcn_sched_barrier(0);
        bf16x8 pa = *(const bf16x8*)&plds[r][g4 * 8];
        // ---- PV
        const float* vrows[8];
#pragma unroll
        for (int j = 0; j < 8; ++j) {
            int pos = pc + g4 * 8 + j;
            vrows[j] = (pos == ctx) ? vnp : vbase + (size_t)pos * (HKV_ * D_);
        }
#pragma unroll
        for (int dt = 0; dt < 8; ++dt) {
            bf16x8 vf;
#pragma unroll
            for (int j = 0; j < 8; ++j) vf[j] = (__bf16)vrows[j][dt * 16 + r];
            acc[dt] = __builtin_amdgcn_mfma_f32_16x16x32_bf16(pa, vf, acc[dt], 0, 0, 0);
        }
        asm volatile("s_waitcnt lgkmcnt(0)" ::: "memory");
        __builtin_amdgcn_sched_barrier(0);
    }
    // ---- finalize l across the 16-lane group
#pragma unroll
    for (int i = 0; i < 4; ++i) {
        float lv = l_run[i];
        lv += __shfl_xor(lv, 1);
        lv += __shfl_xor(lv, 2);
        lv += __shfl_xor(lv, 4);
        lv += __shfl_xor(lv, 8);
        l_run[i] = lv;
    }
    float* pb = part + ((size_t)bg * NSPLIT_ + split) * 16 * 130;
#pragma unroll
    for (int dt = 0; dt < 8; ++dt)
#pragma unroll
        for (int i = 0; i < 4; ++i)
            pb[(g4 * 4 + i) * 130 + dt * 16 + r] = acc[dt][i];
    if (r == 0) {
#pragma unroll
        for (int i = 0; i < 4; ++i) {
            pb[(g4 * 4 + i) * 130 + 128] = m_run[i];
            pb[(g4 * 4 + i) * 130 + 129] = l_run[i];
        }
    }
}

// ---------------------------------------------------------------- attention combine
__global__ __launch_bounds__(256) void attn_comb_k(const float* __restrict__ part,
                                                   const int* __restrict__ ctxl,
                                                   __bf16* __restrict__ ctxb)
{
    int bg = blockIdx.x;
    int b = bg >> 1, g = bg & 1;
    int ctx = ctxl[b];
    int ns = ctx / WAVE_POS_ + 1;
    const float* pb = part + (size_t)bg * NSPLIT_ * 16 * 130;
    __shared__ float Wgt[NSPLIT_][16];
    __shared__ float Dn[16];
    int t = threadIdx.x;
    if (t < 16) {
        int h = t;
        float M = -1e30f;
        for (int s = 0; s < ns; ++s) M = fmaxf(M, pb[(s * 16 + h) * 130 + 128]);
        float den = 0.f;
        for (int s = 0; s < ns; ++s) {
            float w = __expf(pb[(s * 16 + h) * 130 + 128] - M);
            Wgt[s][h] = w;
            den += w * pb[(s * 16 + h) * 130 + 129];
        }
        Dn[h] = den;
    }
    __syncthreads();
    int h = t >> 4, d0 = (t & 15) * 8;
    float o[8];
#pragma unroll
    for (int j = 0; j < 8; ++j) o[j] = 0.f;
    for (int s = 0; s < ns; ++s) {
        float w = Wgt[s][h];
        const float* ap = pb + (s * 16 + h) * 130 + d0;
#pragma unroll
        for (int j = 0; j < 8; ++j) o[j] += w * ap[j];
    }
    float inv = 1.f / Dn[h];
#pragma unroll
    for (int j = 0; j < 8; ++j)
        ctxb[(size_t)b * HID_ + (g * GQ_ + h) * D_ + d0 + j] = (__bf16)(o[j] * inv);
}

// ---------------------------------------------------------------- dense epilogue + residual + rmsnorm2
__global__ __launch_bounds__(256) void dense_epi_k(const float* __restrict__ hidden,
                                                   const float* __restrict__ partd, // [8][32][HID_]
                                                   const float* __restrict__ wln2,
                                                   float* __restrict__ xout,
                                                   __bf16* __restrict__ a2)
{
    __shared__ float xr[HID_];
    int b = blockIdx.x;
    float ss = 0.f;
    for (int i = threadIdx.x; i < HID_; i += 256) {
        float v = hidden[(size_t)b * HID_ + i];
#pragma unroll
        for (int p = 0; p < 8; ++p) v += partd[((size_t)p * B_ + b) * HID_ + i];
        xr[i] = v;
        ss += v * v;
        xout[(size_t)b * HID_ + i] = v;
    }
#pragma unroll
    for (int m = 1; m < 64; m <<= 1) ss += __shfl_xor(ss, m);
    __shared__ float wred[4];
    if ((threadIdx.x & 63) == 0) wred[threadIdx.x >> 6] = ss;
    __syncthreads();
    ss = wred[0] + wred[1] + wred[2] + wred[3];
    float rs = rsqrtf(ss / HID_ + EPS_);
    for (int i = threadIdx.x; i < HID_; i += 256)
        a2[(size_t)b * HID_ + i] = (__bf16)(wln2[i] * xr[i] * rs);
}

// ---------------------------------------------------------------- swiglu activation (sums 2 h4h slabs)
__global__ __launch_bounds__(256) void act_k(const float* __restrict__ gu, // [2][32][2*FFN_]
                                             __bf16* __restrict__ act)
{
    int i = blockIdx.x * 256 + threadIdx.x;
    int b = blockIdx.y;
    if (i < FFN_) {
        const float* g0 = gu + (size_t)b * 2 * FFN_;
        const float* g1 = gu + ((size_t)B_ + b) * 2 * FFN_;
        float gv = g0[i] + g1[i];
        float uv = g0[FFN_ + i] + g1[FFN_ + i];
        float s = gv / (1.f + __expf(-gv));
        act[(size_t)b * FFN_ + i] = (__bf16)(s * uv);
    }
}

// ---------------------------------------------------------------- final residual
__global__ __launch_bounds__(256) void out_epi_k(const float* __restrict__ x,
                                                 const float* __restrict__ part4, // [8][32][HID_]
                                                 float* __restrict__ out)
{
    int i = blockIdx.x * 256 + threadIdx.x;
    float v = x[i];
#pragma unroll
    for (int p = 0; p < 8; ++p) v += part4[(size_t)p * (B_ * HID_) + i];
    out[i] = v;
}

// ---------------------------------------------------------------- launch
extern "C" void kernel_launch(void* const* d_in, const int* in_sizes, int n_in,
                              void* d_out, int out_size, void* d_ws, size_t ws_size,
                              hipStream_t stream)
{
    const float* hidden  = (const float*)d_in[0];
    const int*   ctxl    = (const int*)d_in[1];
    const float* kcache  = (const float*)d_in[2];
    const float* vcache  = (const float*)d_in[3];
    const float* w_ln1   = (const float*)d_in[4];
    const float* w_ln2   = (const float*)d_in[5];
    const float* w_qkv   = (const float*)d_in[6];
    const float* b_qkv   = (const float*)d_in[7];
    const float* w_dense = (const float*)d_in[8];
    const float* w_h4h   = (const float*)d_in[9];
    const float* w_4hh   = (const float*)d_in[10];
    float* out = (float*)d_out;

    char* ws = (char*)d_ws;
    size_t off = 0;
    auto alloc = [&](size_t bytes) -> void* {
        void* p = ws + off;
        off += (bytes + 255) & ~(size_t)255;
        return p;
    };
    __bf16* a0    = (__bf16*)alloc((size_t)B_ * HID_ * 2);
    float*  partq = (float*) alloc((size_t)8 * B_ * NQKV_ * 4);
    __bf16* qbf   = (__bf16*)alloc((size_t)B_ * HID_ * 2);
    float*  knew  = (float*) alloc((size_t)B_ * HKV_ * D_ * 4);
    float*  vnew  = (float*) alloc((size_t)B_ * HKV_ * D_ * 4);
    float*  apart = (float*) alloc((size_t)B_ * HKV_ * NSPLIT_ * 16 * 130 * 4);
    __bf16* ctxb  = (__bf16*)alloc((size_t)B_ * HID_ * 2);
    float*  partd = (float*) alloc((size_t)8 * B_ * HID_ * 4);
    float*  xbuf  = (float*) alloc((size_t)B_ * HID_ * 4);
    __bf16* a2    = (__bf16*)alloc((size_t)B_ * HID_ * 2);
    float*  gu    = (float*) alloc((size_t)2 * B_ * 2 * FFN_ * 4);
    __bf16* actb  = (__bf16*)alloc((size_t)B_ * FFN_ * 2);
    float*  part4 = (float*) alloc((size_t)8 * B_ * HID_ * 4);
    (void)ws_size; (void)in_sizes; (void)n_in; (void)out_size;

    hipLaunchKernelGGL(rmsnorm1_k, dim3(B_), dim3(256), 0, stream, hidden, w_ln1, a0);
    hipLaunchKernelGGL((gemm16<HID_, NQKV_, 8>), dim3(NQKV_ / 32, 8), dim3(256), 0, stream, a0, w_qkv, partq);
    hipLaunchKernelGGL(qkv_epi_k, dim3(B_), dim3(256), 0, stream, partq, b_qkv, ctxl, qbf, knew, vnew);
    hipLaunchKernelGGL(attn_k, dim3(B_ * HKV_, NSPLIT_ / 4), dim3(256), 0, stream,
                       kcache, vcache, knew, vnew, qbf, ctxl, apart);
    hipLaunchKernelGGL(attn_comb_k, dim3(B_ * HKV_), dim3(256), 0, stream, apart, ctxl, ctxb);
    hipLaunchKernelGGL((gemm16<HID_, HID_, 8>), dim3(HID_ / 32, 8), dim3(256), 0, stream, ctxb, w_dense, partd);
    hipLaunchKernelGGL(dense_epi_k, dim3(B_), dim3(256), 0, stream, hidden, partd, w_ln2, xbuf, a2);
    hipLaunchKernelGGL((gemm16<HID_, 2 * FFN_, 2>), dim3(2 * FFN_ / 32, 2), dim3(256), 0, stream, a2, w_h4h, gu);
    hipLaunchKernelGGL(act_k, dim3((FFN_ + 255) / 256, B_), dim3(256), 0, stream, gu, actb);
    hipLaunchKernelGGL((gemm16<FFN_, HID_, 8>), dim3(HID_ / 32, 8), dim3(256), 0, stream, actb, w_4hh, part4);
    hipLaunchKernelGGL(out_epi_k, dim3(B_ * HID_ / 256), dim3(256), 0, stream, xbuf, part4, out);
}

// Round 4
// 290.244 us; speedup vs baseline: 1.1113x; 1.1113x over previous
//
#include <hip/hip_runtime.h>
#include <hip/hip_bf16.h>

#define B_    32
#define L_    4096
#define H_    32
#define HKV_  2
#define GQ_   16
#define D_    128
#define HID_  4096
#define FFN_  13696
#define NQKV_ 4608
#define ROT_  64
#define EPS_  1e-5f

#define WAVE_POS_ 128
#define NSPLIT_   32   // L_ / WAVE_POS_

typedef __attribute__((ext_vector_type(8))) __bf16 bf16x8;
typedef __attribute__((ext_vector_type(4))) float  f32x4;

// ---------------------------------------------------------------- rmsnorm1 (1024 thr)
__global__ __launch_bounds__(1024) void rmsnorm1_k(const float* __restrict__ x,
                                                   const float* __restrict__ w,
                                                   __bf16* __restrict__ out)
{
    int b = blockIdx.x;
    const float* row = x + (size_t)b * HID_;
    float vals[4];
    float ss = 0.f;
#pragma unroll
    for (int i = 0; i < 4; ++i) {
        vals[i] = row[threadIdx.x + i * 1024];
        ss += vals[i] * vals[i];
    }
#pragma unroll
    for (int m = 1; m < 64; m <<= 1) ss += __shfl_xor(ss, m);
    __shared__ float wred[16];
    if ((threadIdx.x & 63) == 0) wred[threadIdx.x >> 6] = ss;
    __syncthreads();
    ss = 0.f;
#pragma unroll
    for (int wv = 0; wv < 16; ++wv) ss += wred[wv];
    float rs = rsqrtf(ss / HID_ + EPS_);
#pragma unroll
    for (int i = 0; i < 4; ++i) {
        int idx = threadIdx.x + i * 1024;
        out[(size_t)b * HID_ + idx] = (__bf16)(w[idx] * vals[i] * rs);
    }
}

// ---------------------------------------------------------------- skinny GEMM (R2-identical)
// A: [32][K] bf16 row-major.  W: [K][N] f32.  Cp: [KSPLIT][32][N] f32 partials.
template<int K, int N, int KSPLIT>
__global__ __launch_bounds__(256) void gemm16(const __bf16* __restrict__ A,
                                              const float* __restrict__ W,
                                              float* __restrict__ Cp)
{
    static_assert(K % 32 == 0, "K");
    constexpr int ksteps = K / 32;
    constexpr int nch    = KSPLIT * 4;
    const int lane = threadIdx.x & 63;
    const int wid  = threadIdx.x >> 6;
    const int n0   = blockIdx.x * 32;
    const int r    = lane & 15;
    const int g4   = lane >> 4;
    const int cid  = blockIdx.y * 4 + wid;
    const int s0   = (ksteps * cid) / nch;
    const int s1   = (ksteps * (cid + 1)) / nch;
    const int kk_b = lane >> 3;        // 0..7
    const int c4   = (lane & 7) * 4;   // 0,4,..,28

    __shared__ __bf16 tiles[4][32][40];   // [wave][col][k(+pad)]
    __bf16 (*tile)[40] = tiles[wid];

    f32x4 acc00 = {0.f,0.f,0.f,0.f}, acc01 = acc00, acc10 = acc00, acc11 = acc00;
    const __bf16* a0p = A + (size_t)r * K;
    const __bf16* a1p = A + (size_t)(r + 16) * K;

    float4 pf[4];
    auto issue = [&](int s) {
        const float* wk = W + (size_t)(s * 32 + kk_b) * N + n0 + c4;
#pragma unroll
        for (int it = 0; it < 4; ++it)
            pf[it] = *(const float4*)(wk + (size_t)(it * 8) * N);
    };

    if (s0 < s1) issue(s0);
    for (int s = s0; s < s1; ++s) {
        float4 cur[4];
#pragma unroll
        for (int it = 0; it < 4; ++it) cur[it] = pf[it];
        if (s + 1 < s1) issue(s + 1);
        // convert + transpose into LDS
#pragma unroll
        for (int it = 0; it < 4; ++it) {
            int kk = it * 8 + kk_b;
            tile[c4 + 0][kk] = (__bf16)cur[it].x;
            tile[c4 + 1][kk] = (__bf16)cur[it].y;
            tile[c4 + 2][kk] = (__bf16)cur[it].z;
            tile[c4 + 3][kk] = (__bf16)cur[it].w;
        }
        asm volatile("s_waitcnt lgkmcnt(0)" ::: "memory");
        __builtin_amdgcn_sched_barrier(0);
        bf16x8 b0  = *(const bf16x8*)&tile[r][g4 * 8];
        bf16x8 b1  = *(const bf16x8*)&tile[r + 16][g4 * 8];
        bf16x8 av0 = *(const bf16x8*)(a0p + s * 32 + g4 * 8);
        bf16x8 av1 = *(const bf16x8*)(a1p + s * 32 + g4 * 8);
        acc00 = __builtin_amdgcn_mfma_f32_16x16x32_bf16(av0, b0, acc00, 0, 0, 0);
        acc10 = __builtin_amdgcn_mfma_f32_16x16x32_bf16(av1, b0, acc10, 0, 0, 0);
        acc01 = __builtin_amdgcn_mfma_f32_16x16x32_bf16(av0, b1, acc01, 0, 0, 0);
        acc11 = __builtin_amdgcn_mfma_f32_16x16x32_bf16(av1, b1, acc11, 0, 0, 0);
        asm volatile("s_waitcnt lgkmcnt(0)" ::: "memory");
        __builtin_amdgcn_sched_barrier(0);
    }

    __shared__ float red[4][32][32];
#pragma unroll
    for (int i = 0; i < 4; ++i) {
        red[wid][g4 * 4 + i][r]           = acc00[i];
        red[wid][g4 * 4 + i][16 + r]      = acc01[i];
        red[wid][16 + g4 * 4 + i][r]      = acc10[i];
        red[wid][16 + g4 * 4 + i][16 + r] = acc11[i];
    }
    __syncthreads();
    for (int idx = threadIdx.x; idx < 1024; idx += 256) {
        int row = idx >> 5, col = idx & 31;
        float v = red[0][row][col] + red[1][row][col] + red[2][row][col] + red[3][row][col];
        Cp[((size_t)blockIdx.y * 32 + row) * N + n0 + col] = v;
    }
}

// ---------------------------------------------------------------- qkv epilogue (1024 thr)
__global__ __launch_bounds__(1024) void qkv_epi_k(const float* __restrict__ part, // [4][32][NQKV_]
                                                  const float* __restrict__ bias,
                                                  const int* __restrict__ ctxl,
                                                  __bf16* __restrict__ qbf,    // [32][4096] roped, *D^-0.5
                                                  float* __restrict__ knew,    // [32][2][128] roped
                                                  float* __restrict__ vnew)    // [32][2][128]
{
    __shared__ float rowv[NQKV_];
    __shared__ float cs[32], sn[32];
    int b = blockIdx.x;
    int pos = ctxl[b];
    if (threadIdx.x < 32) {
        int t = threadIdx.x;
        float inv = powf(10000.f, -(float)t * (1.0f / 32.0f));
        float f = (float)pos * inv;
        float sv, cv; sincosf(f, &sv, &cv);
        cs[t] = cv; sn[t] = sv;
    }
    for (int i = threadIdx.x; i < NQKV_; i += 1024) {
        float v = bias[i];
#pragma unroll
        for (int p = 0; p < 4; ++p) v += part[((size_t)p * B_ + b) * NQKV_ + i];
        rowv[i] = v;
    }
    __syncthreads();
    const float qscale = 0.08838834764831845f; // 1/sqrt(128)
    for (int i = threadIdx.x; i < HID_; i += 1024) {
        int d = i & 127;
        float o;
        if (d < ROT_) {
            int t = d >> 1;
            float cv = cs[t], sv = sn[t];
            float x1 = rowv[i & ~1], x2 = rowv[i | 1];
            o = (d & 1) ? (x2 * cv + x1 * sv) : (x1 * cv - x2 * sv);
        } else o = rowv[i];
        qbf[(size_t)b * HID_ + i] = (__bf16)(o * qscale);
    }
    if (threadIdx.x < HKV_ * D_) {
        int i = threadIdx.x;
        int d = i & 127;
        float o;
        if (d < ROT_) {
            int t = d >> 1;
            float cv = cs[t], sv = sn[t];
            float x1 = rowv[HID_ + (i & ~1)], x2 = rowv[HID_ + (i | 1)];
            o = (d & 1) ? (x2 * cv + x1 * sv) : (x1 * cv - x2 * sv);
        } else o = rowv[HID_ + i];
        knew[(size_t)b * HKV_ * D_ + i] = o;
        vnew[(size_t)b * HKV_ * D_ + i] = rowv[HID_ + HKV_ * D_ + i];
    }
}

// ---------------------------------------------------------------- flash-decode attention (R2-identical)
// part: [B*HKV][NSPLIT_][16][130]  (128 acc, m, l) per head
__global__ __launch_bounds__(256) void attn_k(const float* __restrict__ kc,
                                              const float* __restrict__ vc,
                                              const float* __restrict__ knew,
                                              const float* __restrict__ vnew,
                                              const __bf16* __restrict__ qbf,
                                              const int* __restrict__ ctxl,
                                              float* __restrict__ part)
{
    const int bg  = blockIdx.x;            // 0..63
    const int b   = bg >> 1, g = bg & 1;
    const int wid = threadIdx.x >> 6;
    const int split = blockIdx.y * 4 + wid;  // 0..NSPLIT_-1
    const int ctx = ctxl[b];
    const int p0  = split * WAVE_POS_;
    __shared__ __bf16 plds_all[4][16][40];
    if (p0 > ctx) return;
    const int pend = min(p0 + WAVE_POS_ - 1, ctx);
    const int lane = threadIdx.x & 63;
    const int r = lane & 15, g4 = lane >> 4;

    bf16x8 qf[4];
    {
        const __bf16* qp = qbf + (size_t)b * HID_ + (g * GQ_ + r) * D_ + g4 * 8;
#pragma unroll
        for (int kk = 0; kk < 4; ++kk) qf[kk] = *(const bf16x8*)(qp + kk * 32);
    }
    f32x4 acc[8];
#pragma unroll
    for (int dt = 0; dt < 8; ++dt) acc[dt] = (f32x4){0.f,0.f,0.f,0.f};
    float m_run[4], l_run[4];
#pragma unroll
    for (int i = 0; i < 4; ++i) { m_run[i] = -1e30f; l_run[i] = 0.f; }

    auto plds = plds_all[wid];
    const float* kbase = kc + ((size_t)b * L_ * HKV_ + g) * D_;
    const float* vbase = vc + ((size_t)b * L_ * HKV_ + g) * D_;
    const float* knp = knew + (size_t)(b * HKV_ + g) * D_;
    const float* vnp = vnew + (size_t)(b * HKV_ + g) * D_;

    for (int pc = p0; pc <= pend; pc += 32) {
        // ---- QK^T : scores S[h][p], h=g4*4+i, p = pc + pt*16 + r
        f32x4 sf[2];
#pragma unroll
        for (int pt = 0; pt < 2; ++pt) {
            int pos = pc + pt * 16 + r;
            const float* krow = (pos == ctx) ? knp : kbase + (size_t)pos * (HKV_ * D_);
            f32x4 s = {0.f,0.f,0.f,0.f};
#pragma unroll
            for (int kk = 0; kk < 4; ++kk) {
                const float4* kp = (const float4*)(krow + kk * 32 + g4 * 8);
                float4 fa = kp[0], fb = kp[1];
                bf16x8 kf = { (__bf16)fa.x, (__bf16)fa.y, (__bf16)fa.z, (__bf16)fa.w,
                              (__bf16)fb.x, (__bf16)fb.y, (__bf16)fb.z, (__bf16)fb.w };
                s = __builtin_amdgcn_mfma_f32_16x16x32_bf16(qf[kk], kf, s, 0, 0, 0);
            }
            sf[pt] = s;
        }
        // ---- mask
#pragma unroll
        for (int pt = 0; pt < 2; ++pt) {
            int pos = pc + pt * 16 + r;
            if (pos > ctx) {
#pragma unroll
                for (int i = 0; i < 4; ++i) sf[pt][i] = -1e30f;
            }
        }
        // ---- online softmax (per-head chunk max via 16-lane butterfly)
#pragma unroll
        for (int i = 0; i < 4; ++i) {
            float mv = fmaxf(sf[0][i], sf[1][i]);
            mv = fmaxf(mv, __shfl_xor(mv, 1));
            mv = fmaxf(mv, __shfl_xor(mv, 2));
            mv = fmaxf(mv, __shfl_xor(mv, 4));
            mv = fmaxf(mv, __shfl_xor(mv, 8));
            float mnew = fmaxf(m_run[i], mv);
            float sc = __expf(m_run[i] - mnew);
            l_run[i] *= sc;
            m_run[i] = mnew;
#pragma unroll
            for (int dt = 0; dt < 8; ++dt) acc[dt][i] *= sc;
        }
        // ---- exp, stage P into LDS in PV-A-fragment layout
#pragma unroll
        for (int pt = 0; pt < 2; ++pt) {
#pragma unroll
            for (int i = 0; i < 4; ++i) {
                float e = __expf(sf[pt][i] - m_run[i]);
                l_run[i] += e;
                plds[g4 * 4 + i][pt * 16 + r] = (__bf16)e;
            }
        }
        asm volatile("s_waitcnt lgkmcnt(0)" ::: "memory");
        __builtin_amdgcn_sched_barrier(0);
        bf16x8 pa = *(const bf16x8*)&plds[r][g4 * 8];
        // ---- PV
        const float* vrows[8];
#pragma unroll
        for (int j = 0; j < 8; ++j) {
            int pos = pc + g4 * 8 + j;
            vrows[j] = (pos == ctx) ? vnp : vbase + (size_t)pos * (HKV_ * D_);
        }
#pragma unroll
        for (int dt = 0; dt < 8; ++dt) {
            bf16x8 vf;
#pragma unroll
            for (int j = 0; j < 8; ++j) vf[j] = (__bf16)vrows[j][dt * 16 + r];
            acc[dt] = __builtin_amdgcn_mfma_f32_16x16x32_bf16(pa, vf, acc[dt], 0, 0, 0);
        }
        asm volatile("s_waitcnt lgkmcnt(0)" ::: "memory");
        __builtin_amdgcn_sched_barrier(0);
    }
    // ---- finalize l across the 16-lane group
#pragma unroll
    for (int i = 0; i < 4; ++i) {
        float lv = l_run[i];
        lv += __shfl_xor(lv, 1);
        lv += __shfl_xor(lv, 2);
        lv += __shfl_xor(lv, 4);
        lv += __shfl_xor(lv, 8);
        l_run[i] = lv;
    }
    float* pb = part + ((size_t)bg * NSPLIT_ + split) * 16 * 130;
#pragma unroll
    for (int dt = 0; dt < 8; ++dt)
#pragma unroll
        for (int i = 0; i < 4; ++i)
            pb[(g4 * 4 + i) * 130 + dt * 16 + r] = acc[dt][i];
    if (r == 0) {
#pragma unroll
        for (int i = 0; i < 4; ++i) {
            pb[(g4 * 4 + i) * 130 + 128] = m_run[i];
            pb[(g4 * 4 + i) * 130 + 129] = l_run[i];
        }
    }
}

// ---------------------------------------------------------------- attention combine (parallel)
// grid (B_*HKV_, 2), 1024 threads: block (bg,c) covers d in [c*64, c*64+64)
__global__ __launch_bounds__(1024) void attn_comb_k(const float* __restrict__ part,
                                                    const int* __restrict__ ctxl,
                                                    __bf16* __restrict__ ctxb)
{
    int bg = blockIdx.x;
    int c  = blockIdx.y;
    int b = bg >> 1, g = bg & 1;
    int ctx = ctxl[b];
    int ns = ctx / WAVE_POS_ + 1;
    const float* pb = part + (size_t)bg * NSPLIT_ * 16 * 130;
    __shared__ float mlm[NSPLIT_][16], wgt[NSPLIT_][16];
    __shared__ float Mh[16], Ih[16];
    int t = threadIdx.x;
    if (t < NSPLIT_ * 16) {
        int s = t >> 4, h = t & 15;
        mlm[s][h] = pb[(s * 16 + h) * 130 + 128];
        wgt[s][h] = pb[(s * 16 + h) * 130 + 129];   // temporarily l
    }
    __syncthreads();
    if (t < 16) {
        int h = t;
        float M = -1e30f;
        for (int s = 0; s < ns; ++s) M = fmaxf(M, mlm[s][h]);
        float den = 0.f;
        for (int s = 0; s < ns; ++s) den += __expf(mlm[s][h] - M) * wgt[s][h];
        Mh[h] = M; Ih[h] = 1.f / den;
    }
    __syncthreads();
    if (t < NSPLIT_ * 16) {
        int s = t >> 4, h = t & 15;
        wgt[s][h] = __expf(mlm[s][h] - Mh[h]) * Ih[h];
    }
    __syncthreads();
    int h = t >> 6, dd = (t & 63) + c * 64;
    float o = 0.f;
    for (int s = 0; s < ns; ++s)
        o += wgt[s][h] * pb[(s * 16 + h) * 130 + dd];
    ctxb[(size_t)b * HID_ + (g * GQ_ + h) * D_ + dd] = (__bf16)o;
}

// ---------------------------------------------------------------- dense epilogue + residual + rmsnorm2 (1024 thr)
__global__ __launch_bounds__(1024) void dense_epi_k(const float* __restrict__ hidden,
                                                    const float* __restrict__ partd, // [4][32][HID_]
                                                    const float* __restrict__ wln2,
                                                    float* __restrict__ xout,
                                                    __bf16* __restrict__ a2)
{
    __shared__ float xr[HID_];
    int b = blockIdx.x;
    float ss = 0.f;
    for (int i = threadIdx.x; i < HID_; i += 1024) {
        float v = hidden[(size_t)b * HID_ + i];
#pragma unroll
        for (int p = 0; p < 4; ++p) v += partd[((size_t)p * B_ + b) * HID_ + i];
        xr[i] = v;
        ss += v * v;
        xout[(size_t)b * HID_ + i] = v;
    }
#pragma unroll
    for (int m = 1; m < 64; m <<= 1) ss += __shfl_xor(ss, m);
    __shared__ float wred[16];
    if ((threadIdx.x & 63) == 0) wred[threadIdx.x >> 6] = ss;
    __syncthreads();
    ss = 0.f;
#pragma unroll
    for (int wv = 0; wv < 16; ++wv) ss += wred[wv];
    float rs = rsqrtf(ss / HID_ + EPS_);
    for (int i = threadIdx.x; i < HID_; i += 1024)
        a2[(size_t)b * HID_ + i] = (__bf16)(wln2[i] * xr[i] * rs);
}

// ---------------------------------------------------------------- swiglu activation
__global__ __launch_bounds__(256) void act_k(const float* __restrict__ gu,
                                             __bf16* __restrict__ act)
{
    int i = blockIdx.x * 256 + threadIdx.x;
    int b = blockIdx.y;
    if (i < FFN_) {
        float gv = gu[(size_t)b * 2 * FFN_ + i];
        float uv = gu[(size_t)b * 2 * FFN_ + FFN_ + i];
        float s = gv / (1.f + __expf(-gv));
        act[(size_t)b * FFN_ + i] = (__bf16)(s * uv);
    }
}

// ---------------------------------------------------------------- final residual
__global__ __launch_bounds__(256) void out_epi_k(const float* __restrict__ x,
                                                 const float* __restrict__ part4, // [4][32][HID_]
                                                 float* __restrict__ out)
{
    int i = blockIdx.x * 256 + threadIdx.x;
    float v = x[i];
#pragma unroll
    for (int p = 0; p < 4; ++p) v += part4[(size_t)p * (B_ * HID_) + i];
    out[i] = v;
}

// ---------------------------------------------------------------- launch
extern "C" void kernel_launch(void* const* d_in, const int* in_sizes, int n_in,
                              void* d_out, int out_size, void* d_ws, size_t ws_size,
                              hipStream_t stream)
{
    const float* hidden  = (const float*)d_in[0];
    const int*   ctxl    = (const int*)d_in[1];
    const float* kcache  = (const float*)d_in[2];
    const float* vcache  = (const float*)d_in[3];
    const float* w_ln1   = (const float*)d_in[4];
    const float* w_ln2   = (const float*)d_in[5];
    const float* w_qkv   = (const float*)d_in[6];
    const float* b_qkv   = (const float*)d_in[7];
    const float* w_dense = (const float*)d_in[8];
    const float* w_h4h   = (const float*)d_in[9];
    const float* w_4hh   = (const float*)d_in[10];
    float* out = (float*)d_out;

    char* ws = (char*)d_ws;
    size_t off = 0;
    auto alloc = [&](size_t bytes) -> void* {
        void* p = ws + off;
        off += (bytes + 255) & ~(size_t)255;
        return p;
    };
    __bf16* a0    = (__bf16*)alloc((size_t)B_ * HID_ * 2);
    float*  partq = (float*) alloc((size_t)4 * B_ * NQKV_ * 4);
    __bf16* qbf   = (__bf16*)alloc((size_t)B_ * HID_ * 2);
    float*  knew  = (float*) alloc((size_t)B_ * HKV_ * D_ * 4);
    float*  vnew  = (float*) alloc((size_t)B_ * HKV_ * D_ * 4);
    float*  apart = (float*) alloc((size_t)B_ * HKV_ * NSPLIT_ * 16 * 130 * 4);
    __bf16* ctxb  = (__bf16*)alloc((size_t)B_ * HID_ * 2);
    float*  partd = (float*) alloc((size_t)4 * B_ * HID_ * 4);
    float*  xbuf  = (float*) alloc((size_t)B_ * HID_ * 4);
    __bf16* a2    = (__bf16*)alloc((size_t)B_ * HID_ * 2);
    float*  gu    = (float*) alloc((size_t)B_ * 2 * FFN_ * 4);
    __bf16* actb  = (__bf16*)alloc((size_t)B_ * FFN_ * 2);
    float*  part4 = (float*) alloc((size_t)4 * B_ * HID_ * 4);
    (void)ws_size; (void)in_sizes; (void)n_in; (void)out_size;

    hipLaunchKernelGGL(rmsnorm1_k, dim3(B_), dim3(1024), 0, stream, hidden, w_ln1, a0);
    hipLaunchKernelGGL((gemm16<HID_, NQKV_, 4>), dim3(NQKV_ / 32, 4), dim3(256), 0, stream, a0, w_qkv, partq);
    hipLaunchKernelGGL(qkv_epi_k, dim3(B_), dim3(1024), 0, stream, partq, b_qkv, ctxl, qbf, knew, vnew);
    hipLaunchKernelGGL(attn_k, dim3(B_ * HKV_, NSPLIT_ / 4), dim3(256), 0, stream,
                       kcache, vcache, knew, vnew, qbf, ctxl, apart);
    hipLaunchKernelGGL(attn_comb_k, dim3(B_ * HKV_, 2), dim3(1024), 0, stream, apart, ctxl, ctxb);
    hipLaunchKernelGGL((gemm16<HID_, HID_, 4>), dim3(HID_ / 32, 4), dim3(256), 0, stream, ctxb, w_dense, partd);
    hipLaunchKernelGGL(dense_epi_k, dim3(B_), dim3(1024), 0, stream, hidden, partd, w_ln2, xbuf, a2);
    hipLaunchKernelGGL((gemm16<HID_, 2 * FFN_, 1>), dim3(2 * FFN_ / 32, 1), dim3(256), 0, stream, a2, w_h4h, gu);
    hipLaunchKernelGGL(act_k, dim3((FFN_ + 255) / 256, B_), dim3(256), 0, stream, gu, actb);
    hipLaunchKernelGGL((gemm16<FFN_, HID_, 4>), dim3(HID_ / 32, 4), dim3(256), 0, stream, actb, w_4hh, part4);
    hipLaunchKernelGGL(out_epi_k, dim3(B_ * HID_ / 256), dim3(256), 0, stream, xbuf, part4, out);
}

// Round 5
// 268.950 us; speedup vs baseline: 1.1993x; 1.0792x over previous
//
#include <hip/hip_runtime.h>
#include <hip/hip_bf16.h>

#define B_    32
#define L_    4096
#define H_    32
#define HKV_  2
#define GQ_   16
#define D_    128
#define HID_  4096
#define FFN_  13696
#define NQKV_ 4608
#define ROT_  64
#define EPS_  1e-5f

#define WAVE_POS_ 128
#define NSPLIT_   32   // L_ / WAVE_POS_

// KSPLIT per GEMM (partial-slab counts — epilogues must match)
#define KS_QKV_  16
#define KS_DEN_  16
#define KS_H4H_  4
#define KS_4HH_  16

typedef __attribute__((ext_vector_type(8))) __bf16 bf16x8;
typedef __attribute__((ext_vector_type(4))) float  f32x4;

__device__ __forceinline__ void gl_lds16(const float* g, float* l) {
    __builtin_amdgcn_global_load_lds((const __attribute__((address_space(1))) void*)g,
                                     (__attribute__((address_space(3))) void*)l, 16, 0, 0);
}

// ---------------------------------------------------------------- rmsnorm1 (1024 thr)
__global__ __launch_bounds__(1024) void rmsnorm1_k(const float* __restrict__ x,
                                                   const float* __restrict__ w,
                                                   __bf16* __restrict__ out)
{
    int b = blockIdx.x;
    const float* row = x + (size_t)b * HID_;
    float vals[4];
    float ss = 0.f;
#pragma unroll
    for (int i = 0; i < 4; ++i) {
        vals[i] = row[threadIdx.x + i * 1024];
        ss += vals[i] * vals[i];
    }
#pragma unroll
    for (int m = 1; m < 64; m <<= 1) ss += __shfl_xor(ss, m);
    __shared__ float wred[16];
    if ((threadIdx.x & 63) == 0) wred[threadIdx.x >> 6] = ss;
    __syncthreads();
    ss = 0.f;
#pragma unroll
    for (int wv = 0; wv < 16; ++wv) ss += wred[wv];
    float rs = rsqrtf(ss / HID_ + EPS_);
#pragma unroll
    for (int i = 0; i < 4; ++i) {
        int idx = threadIdx.x + i * 1024;
        out[(size_t)b * HID_ + idx] = (__bf16)(w[idx] * vals[i] * rs);
    }
}

// ---------------------------------------------------------------- skinny GEMM, m201-style staging
// A: [32][K] bf16 row-major.  W: [K][N] f32.  Cp: [KSPLIT][32][N] f32 partials.
// Block: 4 waves x 32-col slabs over a 128-col panel; K split by blockIdx.y.
// Per k-step (32 K): stage [32][128] f32 W-tile to LDS via global_load_lds
// (16 instr, 4/wave), XOR-swizzled source at 32B granularity; triple buffer;
// counted vmcnt(4) + one raw s_barrier per step.
template<int K, int N, int KSPLIT>
__global__ __launch_bounds__(256) void gemm16(const __bf16* __restrict__ A,
                                              const float* __restrict__ W,
                                              float* __restrict__ Cp)
{
    static_assert(K % 32 == 0, "K");
    constexpr int ksteps = K / 32;
    const int lane = threadIdx.x & 63;
    const int wid  = threadIdx.x >> 6;
    const int n0   = blockIdx.x * 128;
    const int cw   = wid * 32;
    const int r    = lane & 15;
    const int g4   = lane >> 4;
    const int s0   = (ksteps * (int)blockIdx.y) / KSPLIT;
    const int s1   = (ksteps * (int)(blockIdx.y + 1)) / KSPLIT;

    __shared__ float tiles[3][32][128];   // 48 KB

    // staging geometry: wave stages rows wid*8 .. wid*8+7; 4 instr x (2 rows)
    const int rhalf = lane >> 5;          // 0/1 row within instruction
    const int mslot = lane & 31;          // 16B slot within row
    auto stage = [&](int s, float* dst) {
        if (s >= s1) return;
#pragma unroll
        for (int it = 0; it < 4; ++it) {
            int row  = wid * 8 + it * 2 + rhalf;
            int gcol = ((((mslot >> 1) ^ (row >> 3)) << 3) | ((mslot & 1) << 2));
            const float* src = W + (size_t)(s * 32 + row) * N + n0 + gcol;
            gl_lds16(src, dst + (size_t)(wid * 8 + it * 2) * 128);
        }
    };

    f32x4 acc00 = {0.f,0.f,0.f,0.f}, acc01 = acc00, acc10 = acc00, acc11 = acc00;
    const __bf16* a0p = A + (size_t)r * K;
    const __bf16* a1p = A + (size_t)(r + 16) * K;

    stage(s0,     &tiles[0][0][0]);
    stage(s0 + 1, &tiles[1][0][0]);

    const int c0 = cw + r, c1 = cw + r + 16;
    const int i0 = (((c0 >> 3) ^ g4) << 3) | (c0 & 7);
    const int i1 = (((c1 >> 3) ^ g4) << 3) | (c1 & 7);

    int bufc = 0;
    for (int s = s0; s < s1; ++s) {
        if (s + 1 < s1) asm volatile("s_waitcnt vmcnt(4)" ::: "memory");
        else            asm volatile("s_waitcnt vmcnt(0)" ::: "memory");
        __builtin_amdgcn_s_barrier();
        __builtin_amdgcn_sched_barrier(0);
        int bs = bufc + 2; if (bs >= 3) bs -= 3;
        stage(s + 2, &tiles[bs][0][0]);

        bf16x8 av0 = *(const bf16x8*)(a0p + s * 32 + g4 * 8);
        bf16x8 av1 = *(const bf16x8*)(a1p + s * 32 + g4 * 8);
        const float (*tile)[128] = tiles[bufc];
        bf16x8 b0f, b1f;
#pragma unroll
        for (int j = 0; j < 8; ++j) {
            b0f[j] = (__bf16)tile[g4 * 8 + j][i0];
            b1f[j] = (__bf16)tile[g4 * 8 + j][i1];
        }
        acc00 = __builtin_amdgcn_mfma_f32_16x16x32_bf16(av0, b0f, acc00, 0, 0, 0);
        acc10 = __builtin_amdgcn_mfma_f32_16x16x32_bf16(av1, b0f, acc10, 0, 0, 0);
        acc01 = __builtin_amdgcn_mfma_f32_16x16x32_bf16(av0, b1f, acc01, 0, 0, 0);
        acc11 = __builtin_amdgcn_mfma_f32_16x16x32_bf16(av1, b1f, acc11, 0, 0, 0);
        bufc = (bufc + 1 < 3) ? bufc + 1 : 0;
    }

    float* cp = Cp + ((size_t)blockIdx.y * 32) * N + n0 + cw;
#pragma unroll
    for (int i = 0; i < 4; ++i) {
        cp[(size_t)(g4 * 4 + i) * N + r]           = acc00[i];
        cp[(size_t)(g4 * 4 + i) * N + r + 16]      = acc01[i];
        cp[(size_t)(16 + g4 * 4 + i) * N + r]      = acc10[i];
        cp[(size_t)(16 + g4 * 4 + i) * N + r + 16] = acc11[i];
    }
}

// ---------------------------------------------------------------- qkv epilogue (1024 thr)
__global__ __launch_bounds__(1024) void qkv_epi_k(const float* __restrict__ part, // [KS_QKV_][32][NQKV_]
                                                  const float* __restrict__ bias,
                                                  const int* __restrict__ ctxl,
                                                  __bf16* __restrict__ qbf,
                                                  float* __restrict__ knew,
                                                  float* __restrict__ vnew)
{
    __shared__ float rowv[NQKV_];
    __shared__ float cs[32], sn[32];
    int b = blockIdx.x;
    int pos = ctxl[b];
    if (threadIdx.x < 32) {
        int t = threadIdx.x;
        float inv = powf(10000.f, -(float)t * (1.0f / 32.0f));
        float f = (float)pos * inv;
        float sv, cv; sincosf(f, &sv, &cv);
        cs[t] = cv; sn[t] = sv;
    }
    for (int i = threadIdx.x; i < NQKV_; i += 1024) {
        float v = bias[i];
#pragma unroll
        for (int p = 0; p < KS_QKV_; ++p) v += part[((size_t)p * B_ + b) * NQKV_ + i];
        rowv[i] = v;
    }
    __syncthreads();
    const float qscale = 0.08838834764831845f; // 1/sqrt(128)
    for (int i = threadIdx.x; i < HID_; i += 1024) {
        int d = i & 127;
        float o;
        if (d < ROT_) {
            int t = d >> 1;
            float cv = cs[t], sv = sn[t];
            float x1 = rowv[i & ~1], x2 = rowv[i | 1];
            o = (d & 1) ? (x2 * cv + x1 * sv) : (x1 * cv - x2 * sv);
        } else o = rowv[i];
        qbf[(size_t)b * HID_ + i] = (__bf16)(o * qscale);
    }
    if (threadIdx.x < HKV_ * D_) {
        int i = threadIdx.x;
        int d = i & 127;
        float o;
        if (d < ROT_) {
            int t = d >> 1;
            float cv = cs[t], sv = sn[t];
            float x1 = rowv[HID_ + (i & ~1)], x2 = rowv[HID_ + (i | 1)];
            o = (d & 1) ? (x2 * cv + x1 * sv) : (x1 * cv - x2 * sv);
        } else o = rowv[HID_ + i];
        knew[(size_t)b * HKV_ * D_ + i] = o;
        vnew[(size_t)b * HKV_ * D_ + i] = rowv[HID_ + HKV_ * D_ + i];
    }
}

// ---------------------------------------------------------------- flash-decode attention (R4-identical)
__global__ __launch_bounds__(256) void attn_k(const float* __restrict__ kc,
                                              const float* __restrict__ vc,
                                              const float* __restrict__ knew,
                                              const float* __restrict__ vnew,
                                              const __bf16* __restrict__ qbf,
                                              const int* __restrict__ ctxl,
                                              float* __restrict__ part)
{
    const int bg  = blockIdx.x;            // 0..63
    const int b   = bg >> 1, g = bg & 1;
    const int wid = threadIdx.x >> 6;
    const int split = blockIdx.y * 4 + wid;  // 0..NSPLIT_-1
    const int ctx = ctxl[b];
    const int p0  = split * WAVE_POS_;
    __shared__ __bf16 plds_all[4][16][40];
    if (p0 > ctx) return;
    const int pend = min(p0 + WAVE_POS_ - 1, ctx);
    const int lane = threadIdx.x & 63;
    const int r = lane & 15, g4 = lane >> 4;

    bf16x8 qf[4];
    {
        const __bf16* qp = qbf + (size_t)b * HID_ + (g * GQ_ + r) * D_ + g4 * 8;
#pragma unroll
        for (int kk = 0; kk < 4; ++kk) qf[kk] = *(const bf16x8*)(qp + kk * 32);
    }
    f32x4 acc[8];
#pragma unroll
    for (int dt = 0; dt < 8; ++dt) acc[dt] = (f32x4){0.f,0.f,0.f,0.f};
    float m_run[4], l_run[4];
#pragma unroll
    for (int i = 0; i < 4; ++i) { m_run[i] = -1e30f; l_run[i] = 0.f; }

    auto plds = plds_all[wid];
    const float* kbase = kc + ((size_t)b * L_ * HKV_ + g) * D_;
    const float* vbase = vc + ((size_t)b * L_ * HKV_ + g) * D_;
    const float* knp = knew + (size_t)(b * HKV_ + g) * D_;
    const float* vnp = vnew + (size_t)(b * HKV_ + g) * D_;

    for (int pc = p0; pc <= pend; pc += 32) {
        f32x4 sf[2];
#pragma unroll
        for (int pt = 0; pt < 2; ++pt) {
            int pos = pc + pt * 16 + r;
            const float* krow = (pos == ctx) ? knp : kbase + (size_t)pos * (HKV_ * D_);
            f32x4 s = {0.f,0.f,0.f,0.f};
#pragma unroll
            for (int kk = 0; kk < 4; ++kk) {
                const float4* kp = (const float4*)(krow + kk * 32 + g4 * 8);
                float4 fa = kp[0], fb = kp[1];
                bf16x8 kf = { (__bf16)fa.x, (__bf16)fa.y, (__bf16)fa.z, (__bf16)fa.w,
                              (__bf16)fb.x, (__bf16)fb.y, (__bf16)fb.z, (__bf16)fb.w };
                s = __builtin_amdgcn_mfma_f32_16x16x32_bf16(qf[kk], kf, s, 0, 0, 0);
            }
            sf[pt] = s;
        }
#pragma unroll
        for (int pt = 0; pt < 2; ++pt) {
            int pos = pc + pt * 16 + r;
            if (pos > ctx) {
#pragma unroll
                for (int i = 0; i < 4; ++i) sf[pt][i] = -1e30f;
            }
        }
#pragma unroll
        for (int i = 0; i < 4; ++i) {
            float mv = fmaxf(sf[0][i], sf[1][i]);
            mv = fmaxf(mv, __shfl_xor(mv, 1));
            mv = fmaxf(mv, __shfl_xor(mv, 2));
            mv = fmaxf(mv, __shfl_xor(mv, 4));
            mv = fmaxf(mv, __shfl_xor(mv, 8));
            float mnew = fmaxf(m_run[i], mv);
            float sc = __expf(m_run[i] - mnew);
            l_run[i] *= sc;
            m_run[i] = mnew;
#pragma unroll
            for (int dt = 0; dt < 8; ++dt) acc[dt][i] *= sc;
        }
#pragma unroll
        for (int pt = 0; pt < 2; ++pt) {
#pragma unroll
            for (int i = 0; i < 4; ++i) {
                float e = __expf(sf[pt][i] - m_run[i]);
                l_run[i] += e;
                plds[g4 * 4 + i][pt * 16 + r] = (__bf16)e;
            }
        }
        asm volatile("s_waitcnt lgkmcnt(0)" ::: "memory");
        __builtin_amdgcn_sched_barrier(0);
        bf16x8 pa = *(const bf16x8*)&plds[r][g4 * 8];
        const float* vrows[8];
#pragma unroll
        for (int j = 0; j < 8; ++j) {
            int pos = pc + g4 * 8 + j;
            vrows[j] = (pos == ctx) ? vnp : vbase + (size_t)pos * (HKV_ * D_);
        }
#pragma unroll
        for (int dt = 0; dt < 8; ++dt) {
            bf16x8 vf;
#pragma unroll
            for (int j = 0; j < 8; ++j) vf[j] = (__bf16)vrows[j][dt * 16 + r];
            acc[dt] = __builtin_amdgcn_mfma_f32_16x16x32_bf16(pa, vf, acc[dt], 0, 0, 0);
        }
        asm volatile("s_waitcnt lgkmcnt(0)" ::: "memory");
        __builtin_amdgcn_sched_barrier(0);
    }
#pragma unroll
    for (int i = 0; i < 4; ++i) {
        float lv = l_run[i];
        lv += __shfl_xor(lv, 1);
        lv += __shfl_xor(lv, 2);
        lv += __shfl_xor(lv, 4);
        lv += __shfl_xor(lv, 8);
        l_run[i] = lv;
    }
    float* pb = part + ((size_t)bg * NSPLIT_ + split) * 16 * 130;
#pragma unroll
    for (int dt = 0; dt < 8; ++dt)
#pragma unroll
        for (int i = 0; i < 4; ++i)
            pb[(g4 * 4 + i) * 130 + dt * 16 + r] = acc[dt][i];
    if (r == 0) {
#pragma unroll
        for (int i = 0; i < 4; ++i) {
            pb[(g4 * 4 + i) * 130 + 128] = m_run[i];
            pb[(g4 * 4 + i) * 130 + 129] = l_run[i];
        }
    }
}

// ---------------------------------------------------------------- attention combine (parallel, R4-identical)
__global__ __launch_bounds__(1024) void attn_comb_k(const float* __restrict__ part,
                                                    const int* __restrict__ ctxl,
                                                    __bf16* __restrict__ ctxb)
{
    int bg = blockIdx.x;
    int c  = blockIdx.y;
    int b = bg >> 1, g = bg & 1;
    int ctx = ctxl[b];
    int ns = ctx / WAVE_POS_ + 1;
    const float* pb = part + (size_t)bg * NSPLIT_ * 16 * 130;
    __shared__ float mlm[NSPLIT_][16], wgt[NSPLIT_][16];
    __shared__ float Mh[16], Ih[16];
    int t = threadIdx.x;
    if (t < NSPLIT_ * 16) {
        int s = t >> 4, h = t & 15;
        mlm[s][h] = pb[(s * 16 + h) * 130 + 128];
        wgt[s][h] = pb[(s * 16 + h) * 130 + 129];
    }
    __syncthreads();
    if (t < 16) {
        int h = t;
        float M = -1e30f;
        for (int s = 0; s < ns; ++s) M = fmaxf(M, mlm[s][h]);
        float den = 0.f;
        for (int s = 0; s < ns; ++s) den += __expf(mlm[s][h] - M) * wgt[s][h];
        Mh[h] = M; Ih[h] = 1.f / den;
    }
    __syncthreads();
    if (t < NSPLIT_ * 16) {
        int s = t >> 4, h = t & 15;
        wgt[s][h] = __expf(mlm[s][h] - Mh[h]) * Ih[h];
    }
    __syncthreads();
    int h = t >> 6, dd = (t & 63) + c * 64;
    float o = 0.f;
    for (int s = 0; s < ns; ++s)
        o += wgt[s][h] * pb[(s * 16 + h) * 130 + dd];
    ctxb[(size_t)b * HID_ + (g * GQ_ + h) * D_ + dd] = (__bf16)o;
}

// ---------------------------------------------------------------- dense epilogue + residual + rmsnorm2 (1024 thr)
__global__ __launch_bounds__(1024) void dense_epi_k(const float* __restrict__ hidden,
                                                    const float* __restrict__ partd, // [KS_DEN_][32][HID_]
                                                    const float* __restrict__ wln2,
                                                    float* __restrict__ xout,
                                                    __bf16* __restrict__ a2)
{
    __shared__ float xr[HID_];
    int b = blockIdx.x;
    float ss = 0.f;
    for (int i = threadIdx.x; i < HID_; i += 1024) {
        float v = hidden[(size_t)b * HID_ + i];
#pragma unroll
        for (int p = 0; p < KS_DEN_; ++p) v += partd[((size_t)p * B_ + b) * HID_ + i];
        xr[i] = v;
        ss += v * v;
        xout[(size_t)b * HID_ + i] = v;
    }
#pragma unroll
    for (int m = 1; m < 64; m <<= 1) ss += __shfl_xor(ss, m);
    __shared__ float wred[16];
    if ((threadIdx.x & 63) == 0) wred[threadIdx.x >> 6] = ss;
    __syncthreads();
    ss = 0.f;
#pragma unroll
    for (int wv = 0; wv < 16; ++wv) ss += wred[wv];
    float rs = rsqrtf(ss / HID_ + EPS_);
    for (int i = threadIdx.x; i < HID_; i += 1024)
        a2[(size_t)b * HID_ + i] = (__bf16)(wln2[i] * xr[i] * rs);
}

// ---------------------------------------------------------------- swiglu activation (sums KS_H4H_ slabs)
__global__ __launch_bounds__(256) void act_k(const float* __restrict__ gu, // [KS_H4H_][32][2*FFN_]
                                             __bf16* __restrict__ act)
{
    int i = blockIdx.x * 256 + threadIdx.x;
    int b = blockIdx.y;
    if (i < FFN_) {
        float gv = 0.f, uv = 0.f;
#pragma unroll
        for (int p = 0; p < KS_H4H_; ++p) {
            const float* gp = gu + ((size_t)p * B_ + b) * 2 * FFN_;
            gv += gp[i];
            uv += gp[FFN_ + i];
        }
        float s = gv / (1.f + __expf(-gv));
        act[(size_t)b * FFN_ + i] = (__bf16)(s * uv);
    }
}

// ---------------------------------------------------------------- final residual
__global__ __launch_bounds__(256) void out_epi_k(const float* __restrict__ x,
                                                 const float* __restrict__ part4, // [KS_4HH_][32][HID_]
                                                 float* __restrict__ out)
{
    int i = blockIdx.x * 256 + threadIdx.x;
    float v = x[i];
#pragma unroll
    for (int p = 0; p < KS_4HH_; ++p) v += part4[(size_t)p * (B_ * HID_) + i];
    out[i] = v;
}

// ---------------------------------------------------------------- launch
extern "C" void kernel_launch(void* const* d_in, const int* in_sizes, int n_in,
                              void* d_out, int out_size, void* d_ws, size_t ws_size,
                              hipStream_t stream)
{
    const float* hidden  = (const float*)d_in[0];
    const int*   ctxl    = (const int*)d_in[1];
    const float* kcache  = (const float*)d_in[2];
    const float* vcache  = (const float*)d_in[3];
    const float* w_ln1   = (const float*)d_in[4];
    const float* w_ln2   = (const float*)d_in[5];
    const float* w_qkv   = (const float*)d_in[6];
    const float* b_qkv   = (const float*)d_in[7];
    const float* w_dense = (const float*)d_in[8];
    const float* w_h4h   = (const float*)d_in[9];
    const float* w_4hh   = (const float*)d_in[10];
    float* out = (float*)d_out;

    char* ws = (char*)d_ws;
    size_t off = 0;
    auto alloc = [&](size_t bytes) -> void* {
        void* p = ws + off;
        off += (bytes + 255) & ~(size_t)255;
        return p;
    };
    __bf16* a0    = (__bf16*)alloc((size_t)B_ * HID_ * 2);
    float*  partq = (float*) alloc((size_t)KS_QKV_ * B_ * NQKV_ * 4);
    __bf16* qbf   = (__bf16*)alloc((size_t)B_ * HID_ * 2);
    float*  knew  = (float*) alloc((size_t)B_ * HKV_ * D_ * 4);
    float*  vnew  = (float*) alloc((size_t)B_ * HKV_ * D_ * 4);
    float*  apart = (float*) alloc((size_t)B_ * HKV_ * NSPLIT_ * 16 * 130 * 4);
    __bf16* ctxb  = (__bf16*)alloc((size_t)B_ * HID_ * 2);
    float*  partd = (float*) alloc((size_t)KS_DEN_ * B_ * HID_ * 4);
    float*  xbuf  = (float*) alloc((size_t)B_ * HID_ * 4);
    __bf16* a2    = (__bf16*)alloc((size_t)B_ * HID_ * 2);
    float*  gu    = (float*) alloc((size_t)KS_H4H_ * B_ * 2 * FFN_ * 4);
    __bf16* actb  = (__bf16*)alloc((size_t)B_ * FFN_ * 2);
    float*  part4 = (float*) alloc((size_t)KS_4HH_ * B_ * HID_ * 4);
    (void)ws_size; (void)in_sizes; (void)n_in; (void)out_size;

    hipLaunchKernelGGL(rmsnorm1_k, dim3(B_), dim3(1024), 0, stream, hidden, w_ln1, a0);
    hipLaunchKernelGGL((gemm16<HID_, NQKV_, KS_QKV_>), dim3(NQKV_ / 128, KS_QKV_), dim3(256), 0, stream, a0, w_qkv, partq);
    hipLaunchKernelGGL(qkv_epi_k, dim3(B_), dim3(1024), 0, stream, partq, b_qkv, ctxl, qbf, knew, vnew);
    hipLaunchKernelGGL(attn_k, dim3(B_ * HKV_, NSPLIT_ / 4), dim3(256), 0, stream,
                       kcache, vcache, knew, vnew, qbf, ctxl, apart);
    hipLaunchKernelGGL(attn_comb_k, dim3(B_ * HKV_, 2), dim3(1024), 0, stream, apart, ctxl, ctxb);
    hipLaunchKernelGGL((gemm16<HID_, HID_, KS_DEN_>), dim3(HID_ / 128, KS_DEN_), dim3(256), 0, stream, ctxb, w_dense, partd);
    hipLaunchKernelGGL(dense_epi_k, dim3(B_), dim3(1024), 0, stream, hidden, partd, w_ln2, xbuf, a2);
    hipLaunchKernelGGL((gemm16<HID_, 2 * FFN_, KS_H4H_>), dim3(2 * FFN_ / 128, KS_H4H_), dim3(256), 0, stream, a2, w_h4h, gu);
    hipLaunchKernelGGL(act_k, dim3((FFN_ + 255) / 256, B_), dim3(256), 0, stream, gu, actb);
    hipLaunchKernelGGL((gemm16<FFN_, HID_, KS_4HH_>), dim3(HID_ / 128, KS_4HH_), dim3(256), 0, stream, actb, w_4hh, part4);
    hipLaunchKernelGGL(out_epi_k, dim3(B_ * HID_ / 256), dim3(256), 0, stream, xbuf, part4, out);
}